// Round 5
// baseline (449.833 us; speedup 1.0000x reference)
//
#include <hip/hip_runtime.h>

#define NN 512
#define CS 384
#define CZ 128
#define NH 12
#define PROJW 1152
#define FEAT 2112
#define OUTC 384
#define KC 33            // split-K chunks for out_gemm (chunk = 64 = 4 tiles of 16)
#define KTILES 4

// workspace float offsets
#define WPROJ 0          // [512][1152]: q 0:192 | k 192:384 | v 384:576 | qp 576:720 | kp 720:864 | vp 864:1152
#define WFEAT 589824     // [512][2112]
#define WW    1671168    // [512*512][12]: bias -> normalized w
#define WKT   4816896    // [336][512]: kT rows 0:192 = k cols, 192:336 = rotated kp cols

// ---------------- K1: fused pre-pass ----------------
// blocks 0..4095     : bias = z @ wb + bb -> ww
// blocks 4096..4287  : proj GEMM + point rotation + kT
// blocks 4288..4479  : out init with bias bo (consumed by out_gemm atomics)
__global__ __launch_bounds__(256) void fused_pre(
    const float* __restrict__ s,
    const float* __restrict__ wq, const float* __restrict__ bq,
    const float* __restrict__ wk, const float* __restrict__ bk,
    const float* __restrict__ wv, const float* __restrict__ bv,
    const float* __restrict__ wqp, const float* __restrict__ bqp,
    const float* __restrict__ wkp, const float* __restrict__ bkp,
    const float* __restrict__ wvp, const float* __restrict__ bvp,
    const float* __restrict__ rot, const float* __restrict__ trans,
    const float* __restrict__ z,
    const float* __restrict__ wb, const float* __restrict__ bb,
    const float* __restrict__ bo,
    float* __restrict__ proj, float* __restrict__ kT,
    float* __restrict__ ww, float* __restrict__ out)
{
    __shared__ float smem[8960];
    int bx = blockIdx.x, tid = threadIdx.x;

    if (bx >= 4288) {            // ---- out init: out[n][c] = bo[c] ----
        int idx4 = (bx - 4288)*256 + tid;        // 49152 float4s
        ((float4*)out)[idx4] = ((const float4*)bo)[idx4 % 96];
        return;
    }

    if (bx < 4096) {             // ---- bias path ----
        float* zl = smem;        // 64*128 XOR-swizzled
        float* sb = smem + 8192; // 64*12
        size_t r0 = (size_t)bx * 64;
        const float4* src = (const float4*)(z + r0*CZ);
        float4 v[8];
        #pragma unroll
        for (int k = 0; k < 8; ++k) v[k] = src[tid + k*256];
        #pragma unroll
        for (int k = 0; k < 8; ++k) {
            int i = tid + k*256;
            int r = i >> 5, c4 = i & 31;
            *(float4*)&zl[r*128 + ((c4 ^ (r & 7)) << 2)] = v[k];
        }
        __syncthreads();
        int r = tid & 63, hg = tid >> 6;
        int h0 = __builtin_amdgcn_readfirstlane(hg * 3);
        const float* wbp = wb + h0;
        float a0 = bb[h0], a1 = bb[h0+1], a2 = bb[h0+2];
        #pragma unroll 8
        for (int c4 = 0; c4 < 32; ++c4) {
            float4 zv = *(const float4*)&zl[r*128 + ((c4 ^ (r & 7)) << 2)];
            int cb = c4*4;
            a0 += zv.x*wbp[cb*12]     + zv.y*wbp[(cb+1)*12]     + zv.z*wbp[(cb+2)*12]     + zv.w*wbp[(cb+3)*12];
            a1 += zv.x*wbp[cb*12 + 1] + zv.y*wbp[(cb+1)*12 + 1] + zv.z*wbp[(cb+2)*12 + 1] + zv.w*wbp[(cb+3)*12 + 1];
            a2 += zv.x*wbp[cb*12 + 2] + zv.y*wbp[(cb+1)*12 + 2] + zv.z*wbp[(cb+2)*12 + 2] + zv.w*wbp[(cb+3)*12 + 2];
        }
        float* sd = &sb[r*12 + h0];
        sd[0] = a0; sd[1] = a1; sd[2] = a2;
        __syncthreads();
        if (tid < 192) ((float4*)(ww + r0*12))[tid] = ((const float4*)sb)[tid];
        return;
    }

    // ---- proj path ----
    float* As = smem;            // 32*68
    float* Ws = smem + 2176;     // 32*52
    int p = bx - 4096;
    int gm0 = (p & 7) * 64;
    int gc0 = (p >> 3) * 48;
    const float *w, *b; int ldw, lc0;
    if      (gc0 < 192) { w = wq;  b = bq;  ldw = 192; lc0 = gc0;       }
    else if (gc0 < 384) { w = wk;  b = bk;  ldw = 192; lc0 = gc0 - 192; }
    else if (gc0 < 576) { w = wv;  b = bv;  ldw = 192; lc0 = gc0 - 384; }
    else if (gc0 < 720) { w = wqp; b = bqp; ldw = 144; lc0 = gc0 - 576; }
    else if (gc0 < 864) { w = wkp; b = bkp; ldw = 144; lc0 = gc0 - 720; }
    else                { w = wvp; b = bvp; ldw = 288; lc0 = gc0 - 864; }

    int mi = tid >> 4, ni = tid & 15;
    int m0 = mi * 4, n0 = ni * 3;
    float acc[4][3] = {};

    for (int k0 = 0; k0 < CS; k0 += 32) {
        for (int idx = tid; idx < 2048; idx += 256) {
            int r = idx >> 5, c = idx & 31;
            As[c*68 + r] = s[(gm0 + r)*CS + k0 + c];
        }
        for (int idx = tid; idx < 1536; idx += 256) {
            int c = idx / 48, j = idx - c*48;
            Ws[c*52 + j] = w[(k0 + c)*ldw + lc0 + j];
        }
        __syncthreads();
        #pragma unroll 8
        for (int kk = 0; kk < 32; ++kk) {
            float4 a = *(const float4*)&As[kk*68 + m0];
            float w0 = Ws[kk*52 + n0], w1 = Ws[kk*52 + n0 + 1], w2 = Ws[kk*52 + n0 + 2];
            acc[0][0] += a.x*w0; acc[0][1] += a.x*w1; acc[0][2] += a.x*w2;
            acc[1][0] += a.y*w0; acc[1][1] += a.y*w1; acc[1][2] += a.y*w2;
            acc[2][0] += a.z*w0; acc[2][1] += a.z*w1; acc[2][2] += a.z*w2;
            acc[3][0] += a.w*w0; acc[3][1] += a.w*w1; acc[3][2] += a.w*w2;
        }
        __syncthreads();
    }

    float b0 = b[lc0 + n0], b1 = b[lc0 + n0 + 1], b2 = b[lc0 + n0 + 2];
    if (gc0 >= 576) {
        #pragma unroll
        for (int i = 0; i < 4; ++i) {
            int gm = gm0 + m0 + i;
            const float* R = rot + gm*9;
            const float* T = trans + gm*3;
            float x = acc[i][0] + b0, y = acc[i][1] + b1, zz = acc[i][2] + b2;
            float gx = R[0]*x + R[1]*y + R[2]*zz + T[0];
            float gy = R[3]*x + R[4]*y + R[5]*zz + T[1];
            float gz = R[6]*x + R[7]*y + R[8]*zz + T[2];
            float* dst = proj + (size_t)gm*PROJW + gc0 + n0;
            dst[0] = gx; dst[1] = gy; dst[2] = gz;
            if (gc0 >= 720 && gc0 < 864) {        // rotated kp -> kT rows 192..335
                int c = 192 + (gc0 - 720) + n0;
                kT[(size_t)(c+0)*NN + gm] = gx;
                kT[(size_t)(c+1)*NN + gm] = gy;
                kT[(size_t)(c+2)*NN + gm] = gz;
            }
        }
    } else {
        #pragma unroll
        for (int i = 0; i < 4; ++i) {
            int gm = gm0 + m0 + i;
            float v0 = acc[i][0] + b0, v1 = acc[i][1] + b1, v2 = acc[i][2] + b2;
            float* dst = proj + (size_t)gm*PROJW + gc0 + n0;
            dst[0] = v0; dst[1] = v1; dst[2] = v2;
            if (gc0 >= 192 && gc0 < 384) {        // k -> kT rows 0..191
                int c = gc0 - 192 + n0;
                kT[(size_t)(c+0)*NN + gm] = v0;
                kT[(size_t)(c+1)*NN + gm] = v1;
                kT[(size_t)(c+2)*NN + gm] = v2;
            }
        }
    }
}

// ---------------- K2b: scores (kT) + softmax + write w + v_out scalar/points/norms ----------------
__global__ __launch_bounds__(512, 4) void score_kernel(
    const float* __restrict__ proj, const float* __restrict__ kT,
    float* __restrict__ ww,                      // bias in, normalized w out
    const int* __restrict__ mask,
    const float* __restrict__ rot, const float* __restrict__ trans,
    float* __restrict__ feat)
{
    int n = blockIdx.x, tid = threadIdx.x;
    __shared__ float s_e[NN*12];     // bias -> scores -> exp -> w, [m][12]
    __shared__ float s_q[336];       // q (192) + rotated qp (144)
    __shared__ float s_pts[288];
    __shared__ float s_red[384];
    __shared__ float s_M[NH], s_S[NH];

    // load bias rows + q row
    {
        const float4* src = (const float4*)(ww + (size_t)n*NN*12);
        float4* dst = (float4*)s_e;
        #pragma unroll
        for (int k = 0; k < 3; ++k) dst[tid + k*512] = src[tid + k*512];
    }
    if (tid < 336) s_q[tid] = proj[(size_t)n*PROJW + (tid < 192 ? tid : 384 + tid)];
    int mn = mask[n];
    __syncthreads();

    // scores via transposed k/kp (lane-coalesced kT loads)
    {
        int m = tid;
        bool ok = (mn != 0) && (mask[m] != 0);
        float sc[12];
        #pragma unroll 2
        for (int h = 0; h < NH; ++h) {
            const float* qh  = &s_q[h*16];
            const float* kTh = kT + (size_t)(h*16)*NN + m;
            float dot = 0.f;
            #pragma unroll
            for (int cc = 0; cc < 16; ++cc) dot += qh[cc] * kTh[(size_t)cc*NN];
            const float* qph  = &s_q[192 + h*12];
            const float* kpTh = kT + (size_t)(192 + h*12)*NN + m;
            float pts = 0.f;
            #pragma unroll
            for (int j = 0; j < 12; ++j) { float d = qph[j] - kpTh[(size_t)j*NN]; pts += d*d; }
            sc[h] = dot*0.25f - 0.5f*pts;
        }
        float* row = &s_e[m*12];
        #pragma unroll
        for (int h = 0; h < NH; ++h) {
            float v = sc[h] + row[h];
            row[h] = ok ? v : -1e30f;
        }
    }
    __syncthreads();
    // max
    if (tid < 384) {
        int i = tid / 12, h = tid - i*12;
        float mx = -1e30f;
        for (int mm = i*16; mm < i*16 + 16; ++mm) mx = fmaxf(mx, s_e[mm*12 + h]);
        s_red[tid] = mx;
    }
    __syncthreads();
    if (tid < NH) {
        float mx = -1e30f;
        #pragma unroll
        for (int i = 0; i < 32; ++i) mx = fmaxf(mx, s_red[i*12 + tid]);
        s_M[tid] = mx;
    }
    __syncthreads();
    // exp in place
    {
        float M[12];
        #pragma unroll
        for (int h = 0; h < NH; ++h) M[h] = s_M[h];
        float* row = &s_e[tid*12];
        float4 a = *(float4*)row, b4 = *(float4*)(row+4), c4 = *(float4*)(row+8);
        a.x = __expf(a.x - M[0]);  a.y = __expf(a.y - M[1]);
        a.z = __expf(a.z - M[2]);  a.w = __expf(a.w - M[3]);
        b4.x = __expf(b4.x - M[4]); b4.y = __expf(b4.y - M[5]);
        b4.z = __expf(b4.z - M[6]); b4.w = __expf(b4.w - M[7]);
        c4.x = __expf(c4.x - M[8]); c4.y = __expf(c4.y - M[9]);
        c4.z = __expf(c4.z - M[10]); c4.w = __expf(c4.w - M[11]);
        *(float4*)row = a; *(float4*)(row+4) = b4; *(float4*)(row+8) = c4;
    }
    __syncthreads();
    // sum
    if (tid < 384) {
        int i = tid / 12, h = tid - i*12;
        float sm = 0.f;
        for (int mm = i*16; mm < i*16 + 16; ++mm) sm += s_e[mm*12 + h];
        s_red[tid] = sm;
    }
    __syncthreads();
    if (tid < NH) {
        float sm = 0.f;
        #pragma unroll
        for (int i = 0; i < 32; ++i) sm += s_red[i*12 + tid];
        s_S[tid] = sm;
    }
    __syncthreads();
    // normalize in place
    {
        float iS[12];
        #pragma unroll
        for (int h = 0; h < NH; ++h) iS[h] = 1.0f / s_S[h];
        float* row = &s_e[tid*12];
        float4 a = *(float4*)row, b4 = *(float4*)(row+4), c4 = *(float4*)(row+8);
        a.x *= iS[0]; a.y *= iS[1]; a.z *= iS[2]; a.w *= iS[3];
        b4.x *= iS[4]; b4.y *= iS[5]; b4.z *= iS[6]; b4.w *= iS[7];
        c4.x *= iS[8]; c4.y *= iS[9]; c4.z *= iS[10]; c4.w *= iS[11];
        *(float4*)row = a; *(float4*)(row+4) = b4; *(float4*)(row+8) = c4;
    }
    __syncthreads();
    // write normalized w back for pair_kernel
    {
        float4* dst = (float4*)(ww + (size_t)n*NN*12);
        const float4* src = (const float4*)s_e;
        #pragma unroll
        for (int k = 0; k < 3; ++k) dst[tid + k*512] = src[tid + k*512];
    }

    float* fout = feat + (size_t)n * FEAT;

    // v_out scalar (192) + points (288)
    {
        int o = tid;
        if (o < 480) {
            int col, h; bool isPt = (o >= 192);
            if (!isPt) { col = 384 + o;       h = o >> 4; }
            else       { int p = o - 192; col = 864 + p; h = p / 24; }
            const float* pc = proj + col;
            float acc0 = 0.f, acc1 = 0.f;
            #pragma unroll 8
            for (int mm = 0; mm < NN; mm += 2) {
                acc0 += s_e[(mm  )*12 + h] * pc[(size_t)(mm  )*PROJW];
                acc1 += s_e[(mm+1)*12 + h] * pc[(size_t)(mm+1)*PROJW];
            }
            float acc = acc0 + acc1;
            if (!isPt) fout[h*176 + (o & 15)] = acc;
            else       s_pts[o - 192] = acc;
        }
    }
    __syncthreads();
    // local transform + norms
    if (tid < 96) {
        int h = tid >> 3, p = tid & 7;
        const float* R = rot + n*9;
        const float* T = trans + n*3;
        float x  = s_pts[h*24 + p*3]     - T[0];
        float y  = s_pts[h*24 + p*3 + 1] - T[1];
        float zz = s_pts[h*24 + p*3 + 2] - T[2];
        float lx = R[0]*x + R[3]*y + R[6]*zz;
        float ly = R[1]*x + R[4]*y + R[7]*zz;
        float lz = R[2]*x + R[5]*y + R[8]*zz;
        float* fo = fout + h*176 + 16;
        fo[p*3] = lx; fo[p*3+1] = ly; fo[p*3+2] = lz;
        fout[h*176 + 40 + p] = sqrtf(lx*lx + ly*ly + lz*lz);
    }
}

// ---------------- K2c: pair features = w . z  (per n, z re-read from L3) ----------------
__global__ __launch_bounds__(512, 4) void pair_kernel(
    const float* __restrict__ ww, const float* __restrict__ z,
    float* __restrict__ feat)
{
    int n = blockIdx.x, tid = threadIdx.x;
    __shared__ float s_w[NN*12];
    __shared__ float s_p[4*NH*128];
    {
        const float4* src = (const float4*)(ww + (size_t)n*NN*12);
        float4* dst = (float4*)s_w;
        #pragma unroll
        for (int k = 0; k < 3; ++k) dst[tid + k*512] = src[tid + k*512];
    }
    __syncthreads();
    int c = tid & 127, mh = tid >> 7;             // c column, m quarter
    const float* zb = z + ((size_t)n*NN + mh*128) * CZ + c;
    float pacc[12] = {};
    #pragma unroll 4
    for (int mm = 0; mm < 128; ++mm) {
        float zv = zb[(size_t)mm * CZ];
        const float* wr = &s_w[(mh*128 + mm)*12];           // broadcast across lanes
        float4 a = *(const float4*)wr, b4 = *(const float4*)(wr+4), c4 = *(const float4*)(wr+8);
        pacc[0] += a.x*zv;  pacc[1] += a.y*zv;  pacc[2] += a.z*zv;  pacc[3] += a.w*zv;
        pacc[4] += b4.x*zv; pacc[5] += b4.y*zv; pacc[6] += b4.z*zv; pacc[7] += b4.w*zv;
        pacc[8] += c4.x*zv; pacc[9] += c4.y*zv; pacc[10] += c4.z*zv; pacc[11] += c4.w*zv;
    }
    #pragma unroll
    for (int h = 0; h < NH; ++h) s_p[(mh*NH + h)*128 + c] = pacc[h];
    __syncthreads();
    {
        float* fout = feat + (size_t)n * FEAT;
        int cc = tid & 127, jh = tid >> 7;
        #pragma unroll
        for (int j = 0; j < 3; ++j) {
            int h = jh*3 + j;
            fout[h*176 + 48 + cc] = s_p[h*128 + cc] + s_p[(NH + h)*128 + cc]
                                  + s_p[(2*NH + h)*128 + cc] + s_p[(3*NH + h)*128 + cc];
        }
    }
}

// ---------------- K3: out GEMM (512x384, K=2112, KC=33 x 64), reg-prefetch, atomic accumulate ----------------
__global__ __launch_bounds__(256) void out_gemm(
    const float* __restrict__ feat, const float* __restrict__ wo,
    float* __restrict__ out)
{
    __shared__ float As[16*68];
    __shared__ float Ws[16*68];
    int tid = threadIdx.x;
    int gm0 = blockIdx.x * 64, gn0 = blockIdx.y * 64;
    int kc = blockIdx.z;
    int kbase = kc * (KTILES*16);
    int mi = tid >> 4, ni = tid & 15;
    int m0 = mi * 4, n0 = ni * 4;
    float acc[4][4] = {};

    int ar = tid >> 4, ac = tid & 15;
    int wr = tid >> 6, wc = tid & 63;

    float fa0, fa1, fa2, fa3, wa0, wa1, wa2, wa3;
    float fb0, fb1, fb2, fb3, wb0, wb1, wb2, wb3;
    {
        const float* fp = feat + (size_t)(gm0 + ar)*FEAT + kbase + ac;
        fa0 = fp[0]; fa1 = fp[16*FEAT]; fa2 = fp[32*FEAT]; fa3 = fp[48*FEAT];
        const float* wp = wo + (size_t)(kbase + wr)*OUTC + gn0 + wc;
        wa0 = wp[0]; wa1 = wp[4*OUTC]; wa2 = wp[8*OUTC]; wa3 = wp[12*OUTC];
    }
    for (int kt = 0; kt < KTILES; ++kt) {
        As[ac*68 + ar]      = fa0;
        As[ac*68 + ar + 16] = fa1;
        As[ac*68 + ar + 32] = fa2;
        As[ac*68 + ar + 48] = fa3;
        Ws[wr*68 + wc]        = wa0;
        Ws[(wr+4)*68 + wc]    = wa1;
        Ws[(wr+8)*68 + wc]    = wa2;
        Ws[(wr+12)*68 + wc]   = wa3;
        if (kt + 1 < KTILES) {
            int k0 = kbase + (kt+1)*16;
            const float* fp = feat + (size_t)(gm0 + ar)*FEAT + k0 + ac;
            fb0 = fp[0]; fb1 = fp[16*FEAT]; fb2 = fp[32*FEAT]; fb3 = fp[48*FEAT];
            const float* wp = wo + (size_t)(k0 + wr)*OUTC + gn0 + wc;
            wb0 = wp[0]; wb1 = wp[4*OUTC]; wb2 = wp[8*OUTC]; wb3 = wp[12*OUTC];
        }
        __syncthreads();
        #pragma unroll
        for (int kk = 0; kk < 16; ++kk) {
            float4 a = *(const float4*)&As[kk*68 + m0];
            float4 w = *(const float4*)&Ws[kk*68 + n0];
            acc[0][0] += a.x*w.x; acc[0][1] += a.x*w.y; acc[0][2] += a.x*w.z; acc[0][3] += a.x*w.w;
            acc[1][0] += a.y*w.x; acc[1][1] += a.y*w.y; acc[1][2] += a.y*w.z; acc[1][3] += a.y*w.w;
            acc[2][0] += a.z*w.x; acc[2][1] += a.z*w.y; acc[2][2] += a.z*w.z; acc[2][3] += a.z*w.w;
            acc[3][0] += a.w*w.x; acc[3][1] += a.w*w.y; acc[3][2] += a.w*w.z; acc[3][3] += a.w*w.w;
        }
        __syncthreads();
        fa0 = fb0; fa1 = fb1; fa2 = fb2; fa3 = fb3;
        wa0 = wb0; wa1 = wb1; wa2 = wb2; wa3 = wb3;
    }
    #pragma unroll
    for (int i = 0; i < 4; ++i) {
        float* op = &out[(size_t)(gm0 + m0 + i)*OUTC + gn0 + n0];
        unsafeAtomicAdd(op + 0, acc[i][0]);
        unsafeAtomicAdd(op + 1, acc[i][1]);
        unsafeAtomicAdd(op + 2, acc[i][2]);
        unsafeAtomicAdd(op + 3, acc[i][3]);
    }
}

extern "C" void kernel_launch(void* const* d_in, const int* in_sizes, int n_in,
                              void* d_out, int out_size, void* d_ws, size_t ws_size,
                              hipStream_t stream) {
    (void)in_sizes; (void)n_in; (void)out_size; (void)ws_size;
    const float* s     = (const float*)d_in[0];
    const float* z     = (const float*)d_in[1];
    const float* trans = (const float*)d_in[2];
    const float* rot   = (const float*)d_in[3];
    const int*   mask  = (const int*)d_in[4];
    const float* wq    = (const float*)d_in[5];
    const float* bq    = (const float*)d_in[6];
    const float* wk    = (const float*)d_in[7];
    const float* bk    = (const float*)d_in[8];
    const float* wv    = (const float*)d_in[9];
    const float* bv    = (const float*)d_in[10];
    const float* wqp   = (const float*)d_in[11];
    const float* bqp   = (const float*)d_in[12];
    const float* wkp   = (const float*)d_in[13];
    const float* bkp   = (const float*)d_in[14];
    const float* wvp   = (const float*)d_in[15];
    const float* bvp   = (const float*)d_in[16];
    const float* wb    = (const float*)d_in[17];
    const float* bb    = (const float*)d_in[18];
    const float* wo    = (const float*)d_in[19];
    const float* bo    = (const float*)d_in[20];
    float* ws  = (float*)d_ws;
    float* out = (float*)d_out;

    fused_pre<<<4480, 256, 0, stream>>>(
        s, wq, bq, wk, bk, wv, bv, wqp, bqp, wkp, bkp, wvp, bvp, rot, trans,
        z, wb, bb, bo, ws + WPROJ, ws + WKT, ws + WW, out);
    score_kernel<<<NN, 512, 0, stream>>>(ws + WPROJ, ws + WKT, ws + WW, mask, rot, trans, ws + WFEAT);
    pair_kernel<<<NN, 512, 0, stream>>>(ws + WW, z, ws + WFEAT);
    out_gemm<<<dim3(8, 6, KC), 256, 0, stream>>>(ws + WFEAT, wo, out);
}

// Round 6
// 402.887 us; speedup vs baseline: 1.1165x; 1.1165x over previous
//
#include <hip/hip_runtime.h>

#define NN 512
#define CS 384
#define CZ 128
#define NH 12
#define PROJW 1152
#define FEAT 2112
#define OUTC 384
#define KC 12            // split-K chunks for out_gemm
#define KTILES 11        // K-tiles of 16 per chunk (12*11*16 = 2112)

// workspace float offsets
#define WPROJ 0          // [512][1152]: q 0:192 | k 192:384 | v 384:576 | qp 576:720 | kp 720:864 | vp 864:1152
#define WFEAT 589824     // [512][2112]
#define WW    1671168    // [512*512][12]: bias -> normalized w ; REUSED later as split-K pout
#define WOUTP 1671168    // [12][512][384] split-K partials (written after pair_kernel done reading WW)
#define WKT   4816896    // [336][512]: kT rows 0:192 = k cols, 192:336 = rotated kp cols

// ---------------- K1a: bias = z @ wb + bb  -> ww[nm][12]  (4096 blocks, HBM-bound) ----------------
__global__ __launch_bounds__(256) void bias_gemm(
    const float* __restrict__ z,
    const float* __restrict__ wb, const float* __restrict__ bb,
    float* __restrict__ ww)
{
    __shared__ float zl[64*128];     // XOR-swizzled float4 rows
    __shared__ float sb[64*12];
    int tid = threadIdx.x;
    size_t r0 = (size_t)blockIdx.x * 64;          // global nm row base

    const float4* src = (const float4*)(z + r0*CZ);
    float4 v[8];
    #pragma unroll
    for (int k = 0; k < 8; ++k) v[k] = src[tid + k*256];
    #pragma unroll
    for (int k = 0; k < 8; ++k) {
        int i = tid + k*256;
        int r = i >> 5, c4 = i & 31;
        *(float4*)&zl[r*128 + ((c4 ^ (r & 7)) << 2)] = v[k];
    }
    __syncthreads();

    int r = tid & 63, hg = tid >> 6;              // wave-uniform hg
    int h0 = __builtin_amdgcn_readfirstlane(hg * 3);
    const float* wbp = wb + h0;
    float a0 = bb[h0], a1 = bb[h0+1], a2 = bb[h0+2];
    #pragma unroll 8
    for (int c4 = 0; c4 < 32; ++c4) {
        float4 zv = *(const float4*)&zl[r*128 + ((c4 ^ (r & 7)) << 2)];
        int cb = c4*4;
        a0 += zv.x*wbp[cb*12]     + zv.y*wbp[(cb+1)*12]     + zv.z*wbp[(cb+2)*12]     + zv.w*wbp[(cb+3)*12];
        a1 += zv.x*wbp[cb*12 + 1] + zv.y*wbp[(cb+1)*12 + 1] + zv.z*wbp[(cb+2)*12 + 1] + zv.w*wbp[(cb+3)*12 + 1];
        a2 += zv.x*wbp[cb*12 + 2] + zv.y*wbp[(cb+1)*12 + 2] + zv.z*wbp[(cb+2)*12 + 2] + zv.w*wbp[(cb+3)*12 + 2];
    }
    float* sd = &sb[r*12 + h0];
    sd[0] = a0; sd[1] = a1; sd[2] = a2;
    __syncthreads();
    if (tid < 192) ((float4*)(ww + r0*12))[tid] = ((const float4*)sb)[tid];
}

// ---------------- K1b: proj GEMM (512x1152, K=384) + bias + fused point rotation + kT ----------------
__global__ __launch_bounds__(256) void proj_gemm(
    const float* __restrict__ s,
    const float* __restrict__ wq, const float* __restrict__ bq,
    const float* __restrict__ wk, const float* __restrict__ bk,
    const float* __restrict__ wv, const float* __restrict__ bv,
    const float* __restrict__ wqp, const float* __restrict__ bqp,
    const float* __restrict__ wkp, const float* __restrict__ bkp,
    const float* __restrict__ wvp, const float* __restrict__ bvp,
    const float* __restrict__ rot, const float* __restrict__ trans,
    float* __restrict__ proj, float* __restrict__ kT)
{
    __shared__ float As[32*68];
    __shared__ float Ws[32*52];
    int tid = threadIdx.x;
    int gm0 = blockIdx.x * 64;
    int gc0 = blockIdx.y * 48;
    const float *w, *b; int ldw, lc0;
    if      (gc0 < 192) { w = wq;  b = bq;  ldw = 192; lc0 = gc0;       }
    else if (gc0 < 384) { w = wk;  b = bk;  ldw = 192; lc0 = gc0 - 192; }
    else if (gc0 < 576) { w = wv;  b = bv;  ldw = 192; lc0 = gc0 - 384; }
    else if (gc0 < 720) { w = wqp; b = bqp; ldw = 144; lc0 = gc0 - 576; }
    else if (gc0 < 864) { w = wkp; b = bkp; ldw = 144; lc0 = gc0 - 720; }
    else                { w = wvp; b = bvp; ldw = 288; lc0 = gc0 - 864; }

    int mi = tid >> 4, ni = tid & 15;
    int m0 = mi * 4, n0 = ni * 3;
    float acc[4][3] = {};

    for (int k0 = 0; k0 < CS; k0 += 32) {
        for (int idx = tid; idx < 2048; idx += 256) {
            int r = idx >> 5, c = idx & 31;
            As[c*68 + r] = s[(gm0 + r)*CS + k0 + c];
        }
        for (int idx = tid; idx < 1536; idx += 256) {
            int c = idx / 48, j = idx - c*48;
            Ws[c*52 + j] = w[(k0 + c)*ldw + lc0 + j];
        }
        __syncthreads();
        #pragma unroll 8
        for (int kk = 0; kk < 32; ++kk) {
            float4 a = *(const float4*)&As[kk*68 + m0];
            float w0 = Ws[kk*52 + n0], w1 = Ws[kk*52 + n0 + 1], w2 = Ws[kk*52 + n0 + 2];
            acc[0][0] += a.x*w0; acc[0][1] += a.x*w1; acc[0][2] += a.x*w2;
            acc[1][0] += a.y*w0; acc[1][1] += a.y*w1; acc[1][2] += a.y*w2;
            acc[2][0] += a.z*w0; acc[2][1] += a.z*w1; acc[2][2] += a.z*w2;
            acc[3][0] += a.w*w0; acc[3][1] += a.w*w1; acc[3][2] += a.w*w2;
        }
        __syncthreads();
    }

    float b0 = b[lc0 + n0], b1 = b[lc0 + n0 + 1], b2 = b[lc0 + n0 + 2];
    if (gc0 >= 576) {
        #pragma unroll
        for (int i = 0; i < 4; ++i) {
            int gm = gm0 + m0 + i;
            const float* R = rot + gm*9;
            const float* T = trans + gm*3;
            float x = acc[i][0] + b0, y = acc[i][1] + b1, zz = acc[i][2] + b2;
            float gx = R[0]*x + R[1]*y + R[2]*zz + T[0];
            float gy = R[3]*x + R[4]*y + R[5]*zz + T[1];
            float gz = R[6]*x + R[7]*y + R[8]*zz + T[2];
            float* dst = proj + (size_t)gm*PROJW + gc0 + n0;
            dst[0] = gx; dst[1] = gy; dst[2] = gz;
            if (gc0 >= 720 && gc0 < 864) {        // rotated kp -> kT rows 192..335
                int c = 192 + (gc0 - 720) + n0;
                kT[(size_t)(c+0)*NN + gm] = gx;
                kT[(size_t)(c+1)*NN + gm] = gy;
                kT[(size_t)(c+2)*NN + gm] = gz;
            }
        }
    } else {
        #pragma unroll
        for (int i = 0; i < 4; ++i) {
            int gm = gm0 + m0 + i;
            float v0 = acc[i][0] + b0, v1 = acc[i][1] + b1, v2 = acc[i][2] + b2;
            float* dst = proj + (size_t)gm*PROJW + gc0 + n0;
            dst[0] = v0; dst[1] = v1; dst[2] = v2;
            if (gc0 >= 192 && gc0 < 384) {        // k -> kT rows 0..191
                int c = gc0 - 192 + n0;
                kT[(size_t)(c+0)*NN + gm] = v0;
                kT[(size_t)(c+1)*NN + gm] = v1;
                kT[(size_t)(c+2)*NN + gm] = v2;
            }
        }
    }
}

// ---------------- K2: scores + softmax + w writeback + v_out (1024 threads, h/m-split) ----------------
__global__ __launch_bounds__(1024, 4) void score_kernel(
    const float* __restrict__ proj, const float* __restrict__ kT,
    float* __restrict__ ww,                      // bias in, normalized w out
    const int* __restrict__ mask,
    const float* __restrict__ rot, const float* __restrict__ trans,
    float* __restrict__ feat)
{
    int n = blockIdx.x, tid = threadIdx.x;
    __shared__ float s_e[NN*12];     // bias -> scores -> exp -> w, [m][12]
    __shared__ float s_q[336];       // q (192) + rotated qp (144)
    __shared__ float s_acc[2*480];   // phase F segment partials
    __shared__ float s_pts[288];
    __shared__ float s_red[768];
    __shared__ float s_M[NH], s_S[NH];

    // load bias rows + q row
    {
        const float4* src = (const float4*)(ww + (size_t)n*NN*12);
        float4* dst = (float4*)s_e;
        dst[tid] = src[tid];
        if (tid < 512) dst[tid + 1024] = src[tid + 1024];
    }
    if (tid < 336) s_q[tid] = proj[(size_t)n*PROJW + (tid < 192 ? tid : 384 + tid)];
    int mn = mask[n];
    __syncthreads();

    // phase A: scores; thread (hh = tid>>9, m = tid&511) does heads hh*6..hh*6+5
    {
        int m = tid & 511, h0 = (tid >> 9) * 6;
        bool ok = (mn != 0) && (mask[m] != 0);
        float sc[6];
        #pragma unroll
        for (int j = 0; j < 6; ++j) {
            int h = h0 + j;
            const float* qh  = &s_q[h*16];
            const float* kTh = kT + (size_t)(h*16)*NN + m;
            float dot = 0.f;
            #pragma unroll
            for (int cc = 0; cc < 16; ++cc) dot += qh[cc] * kTh[(size_t)cc*NN];
            const float* qph  = &s_q[192 + h*12];
            const float* kpTh = kT + (size_t)(192 + h*12)*NN + m;
            float pts = 0.f;
            #pragma unroll
            for (int jj = 0; jj < 12; ++jj) { float d = qph[jj] - kpTh[(size_t)jj*NN]; pts += d*d; }
            sc[j] = dot*0.25f - 0.5f*pts;
        }
        float* row = &s_e[m*12 + h0];
        #pragma unroll
        for (int j = 0; j < 6; ++j) {
            float v = sc[j] + row[j];
            row[j] = ok ? v : -1e30f;
        }
    }
    __syncthreads();
    // max: 64 groups of 8 rows
    if (tid < 768) {
        int i = tid / 12, h = tid - i*12;
        float mx = -1e30f;
        for (int mm = i*8; mm < i*8 + 8; ++mm) mx = fmaxf(mx, s_e[mm*12 + h]);
        s_red[tid] = mx;
    }
    __syncthreads();
    if (tid < NH) {
        float mx = -1e30f;
        #pragma unroll
        for (int i = 0; i < 64; ++i) mx = fmaxf(mx, s_red[i*12 + tid]);
        s_M[tid] = mx;
    }
    __syncthreads();
    // exp in place: half-row per thread
    {
        int m = tid & 511, h0 = (tid >> 9) * 6;
        float* row = &s_e[m*12 + h0];
        #pragma unroll
        for (int j = 0; j < 6; ++j) row[j] = __expf(row[j] - s_M[h0 + j]);
    }
    __syncthreads();
    // sum
    if (tid < 768) {
        int i = tid / 12, h = tid - i*12;
        float sm = 0.f;
        for (int mm = i*8; mm < i*8 + 8; ++mm) sm += s_e[mm*12 + h];
        s_red[tid] = sm;
    }
    __syncthreads();
    if (tid < NH) {
        float sm = 0.f;
        #pragma unroll
        for (int i = 0; i < 64; ++i) sm += s_red[i*12 + tid];
        s_S[tid] = sm;
    }
    __syncthreads();
    // normalize in place
    {
        int m = tid & 511, h0 = (tid >> 9) * 6;
        float* row = &s_e[m*12 + h0];
        float i0 = 1.0f / s_S[h0], i1 = 1.0f / s_S[h0+1], i2 = 1.0f / s_S[h0+2];
        float i3 = 1.0f / s_S[h0+3], i4 = 1.0f / s_S[h0+4], i5 = 1.0f / s_S[h0+5];
        row[0] *= i0; row[1] *= i1; row[2] *= i2;
        row[3] *= i3; row[4] *= i4; row[5] *= i5;
    }
    __syncthreads();
    // write normalized w back for pair_kernel
    {
        float4* dst = (float4*)(ww + (size_t)n*NN*12);
        const float4* src = (const float4*)s_e;
        dst[tid] = src[tid];
        if (tid < 512) dst[tid + 1024] = src[tid + 1024];
    }

    float* fout = feat + (size_t)n * FEAT;

    // phase F: v_out scalar (192) + points (288); m split in two segments of 256
    {
        int o = tid & 511, seg = tid >> 9;
        if (o < 480) {
            int col, h; bool isPt = (o >= 192);
            if (!isPt) { col = 384 + o;       h = o >> 4; }
            else       { int p = o - 192; col = 864 + p; h = p / 24; }
            const float* pc = proj + col;
            int mbeg = seg * 256;
            float acc0 = 0.f, acc1 = 0.f;
            #pragma unroll 8
            for (int mm = mbeg; mm < mbeg + 256; mm += 2) {
                acc0 += s_e[(mm  )*12 + h] * pc[(size_t)(mm  )*PROJW];
                acc1 += s_e[(mm+1)*12 + h] * pc[(size_t)(mm+1)*PROJW];
            }
            s_acc[seg*480 + o] = acc0 + acc1;
        }
    }
    __syncthreads();
    if (tid < 480) {
        float acc = s_acc[tid] + s_acc[480 + tid];
        if (tid < 192) { int h = tid >> 4; fout[h*176 + (tid & 15)] = acc; }
        else           { s_pts[tid - 192] = acc; }
    }
    __syncthreads();
    // local transform + norms
    if (tid < 96) {
        int h = tid >> 3, p = tid & 7;
        const float* R = rot + n*9;
        const float* T = trans + n*3;
        float x  = s_pts[h*24 + p*3]     - T[0];
        float y  = s_pts[h*24 + p*3 + 1] - T[1];
        float zz = s_pts[h*24 + p*3 + 2] - T[2];
        float lx = R[0]*x + R[3]*y + R[6]*zz;
        float ly = R[1]*x + R[4]*y + R[7]*zz;
        float lz = R[2]*x + R[5]*y + R[8]*zz;
        float* fo = fout + h*176 + 16;
        fo[p*3] = lx; fo[p*3+1] = ly; fo[p*3+2] = lz;
        fout[h*176 + 40 + p] = sqrtf(lx*lx + ly*ly + lz*lz);
    }
}

// ---------------- K3: pair features = w . z  (1024 threads, h-split x m-quarters) ----------------
__global__ __launch_bounds__(1024, 4) void pair_kernel(
    const float* __restrict__ ww, const float* __restrict__ z,
    float* __restrict__ feat)
{
    int n = blockIdx.x, tid = threadIdx.x;
    __shared__ float s_w[NN*12];
    __shared__ float s_p[4*NH*128];
    {
        const float4* src = (const float4*)(ww + (size_t)n*NN*12);
        float4* dst = (float4*)s_w;
        dst[tid] = src[tid];
        if (tid < 512) dst[tid + 1024] = src[tid + 1024];
    }
    __syncthreads();
    int c = tid & 127;                   // column 0..127
    int mh = (tid >> 7) & 3;             // m quarter
    int h0 = (tid >> 9) * 6;             // h half: 0..5 or 6..11
    const float* zb = z + ((size_t)n*NN + mh*128) * CZ + c;
    float pacc[6] = {};
    #pragma unroll 4
    for (int mm = 0; mm < 128; ++mm) {
        float zv = zb[(size_t)mm * CZ];
        const float* wr = &s_w[(mh*128 + mm)*12 + h0];      // wave-uniform -> broadcast
        pacc[0] += wr[0]*zv; pacc[1] += wr[1]*zv; pacc[2] += wr[2]*zv;
        pacc[3] += wr[3]*zv; pacc[4] += wr[4]*zv; pacc[5] += wr[5]*zv;
    }
    #pragma unroll
    for (int j = 0; j < 6; ++j) s_p[(mh*NH + h0 + j)*128 + c] = pacc[j];
    __syncthreads();
    {
        float* fout = feat + (size_t)n * FEAT;
        for (int idx = tid; idx < 1536; idx += 1024) {
            int h = idx >> 7, cc = idx & 127;
            fout[h*176 + 48 + cc] = s_p[h*128 + cc] + s_p[(NH + h)*128 + cc]
                                  + s_p[(2*NH + h)*128 + cc] + s_p[(3*NH + h)*128 + cc];
        }
    }
}

// ---------------- K4: out GEMM split-K partials (512x384, K=2112, KC=12 x 176), reg-prefetch ----------------
__global__ __launch_bounds__(256) void out_gemm(
    const float* __restrict__ feat, const float* __restrict__ wo,
    float* __restrict__ pout)
{
    __shared__ float As[16*68];
    __shared__ float Ws[16*68];
    int tid = threadIdx.x;
    int gm0 = blockIdx.x * 64, gn0 = blockIdx.y * 64;
    int kc = blockIdx.z;
    int kbase = kc * (KTILES*16);
    int mi = tid >> 4, ni = tid & 15;
    int m0 = mi * 4, n0 = ni * 4;
    float acc[4][4] = {};

    int ar = tid >> 4, ac = tid & 15;
    int wr = tid >> 6, wc = tid & 63;

    float fa0, fa1, fa2, fa3, wa0, wa1, wa2, wa3;
    float fb0, fb1, fb2, fb3, wb0, wb1, wb2, wb3;
    {
        const float* fp = feat + (size_t)(gm0 + ar)*FEAT + kbase + ac;
        fa0 = fp[0]; fa1 = fp[16*FEAT]; fa2 = fp[32*FEAT]; fa3 = fp[48*FEAT];
        const float* wp = wo + (size_t)(kbase + wr)*OUTC + gn0 + wc;
        wa0 = wp[0]; wa1 = wp[4*OUTC]; wa2 = wp[8*OUTC]; wa3 = wp[12*OUTC];
    }
    for (int kt = 0; kt < KTILES; ++kt) {
        As[ac*68 + ar]      = fa0;
        As[ac*68 + ar + 16] = fa1;
        As[ac*68 + ar + 32] = fa2;
        As[ac*68 + ar + 48] = fa3;
        Ws[wr*68 + wc]        = wa0;
        Ws[(wr+4)*68 + wc]    = wa1;
        Ws[(wr+8)*68 + wc]    = wa2;
        Ws[(wr+12)*68 + wc]   = wa3;
        if (kt + 1 < KTILES) {
            int k0 = kbase + (kt+1)*16;
            const float* fp = feat + (size_t)(gm0 + ar)*FEAT + k0 + ac;
            fb0 = fp[0]; fb1 = fp[16*FEAT]; fb2 = fp[32*FEAT]; fb3 = fp[48*FEAT];
            const float* wp = wo + (size_t)(k0 + wr)*OUTC + gn0 + wc;
            wb0 = wp[0]; wb1 = wp[4*OUTC]; wb2 = wp[8*OUTC]; wb3 = wp[12*OUTC];
        }
        __syncthreads();
        #pragma unroll
        for (int kk = 0; kk < 16; ++kk) {
            float4 a = *(const float4*)&As[kk*68 + m0];
            float4 w = *(const float4*)&Ws[kk*68 + n0];
            acc[0][0] += a.x*w.x; acc[0][1] += a.x*w.y; acc[0][2] += a.x*w.z; acc[0][3] += a.x*w.w;
            acc[1][0] += a.y*w.x; acc[1][1] += a.y*w.y; acc[1][2] += a.y*w.z; acc[1][3] += a.y*w.w;
            acc[2][0] += a.z*w.x; acc[2][1] += a.z*w.y; acc[2][2] += a.z*w.z; acc[2][3] += a.z*w.w;
            acc[3][0] += a.w*w.x; acc[3][1] += a.w*w.y; acc[3][2] += a.w*w.z; acc[3][3] += a.w*w.w;
        }
        __syncthreads();
        fa0 = fb0; fa1 = fb1; fa2 = fb2; fa3 = fb3;
        wa0 = wb0; wa1 = wb1; wa2 = wb2; wa3 = wb3;
    }
    float* pb = pout + (size_t)kc * (NN*OUTC);
    #pragma unroll
    for (int i = 0; i < 4; ++i)
        *(float4*)&pb[(size_t)(gm0 + m0 + i)*OUTC + gn0 + n0] =
            make_float4(acc[i][0], acc[i][1], acc[i][2], acc[i][3]);
}

// ---------------- K5: reduce partials + bias ----------------
__global__ __launch_bounds__(256) void out_reduce(
    const float* __restrict__ pout, const float* __restrict__ bo,
    float* __restrict__ out)
{
    int idx4 = blockIdx.x * 256 + threadIdx.x;   // 49152 float4s
    int col4 = idx4 % 96;
    const float4* b4 = (const float4*)bo;
    float4 acc = b4[col4];
    #pragma unroll
    for (int kc = 0; kc < KC; ++kc) {
        float4 p = ((const float4*)(pout + (size_t)kc*(NN*OUTC)))[idx4];
        acc.x += p.x; acc.y += p.y; acc.z += p.z; acc.w += p.w;
    }
    ((float4*)out)[idx4] = acc;
}

extern "C" void kernel_launch(void* const* d_in, const int* in_sizes, int n_in,
                              void* d_out, int out_size, void* d_ws, size_t ws_size,
                              hipStream_t stream) {
    (void)in_sizes; (void)n_in; (void)out_size; (void)ws_size;
    const float* s     = (const float*)d_in[0];
    const float* z     = (const float*)d_in[1];
    const float* trans = (const float*)d_in[2];
    const float* rot   = (const float*)d_in[3];
    const int*   mask  = (const int*)d_in[4];
    const float* wq    = (const float*)d_in[5];
    const float* bq    = (const float*)d_in[6];
    const float* wk    = (const float*)d_in[7];
    const float* bk    = (const float*)d_in[8];
    const float* wv    = (const float*)d_in[9];
    const float* bv    = (const float*)d_in[10];
    const float* wqp   = (const float*)d_in[11];
    const float* bqp   = (const float*)d_in[12];
    const float* wkp   = (const float*)d_in[13];
    const float* bkp   = (const float*)d_in[14];
    const float* wvp   = (const float*)d_in[15];
    const float* bvp   = (const float*)d_in[16];
    const float* wb    = (const float*)d_in[17];
    const float* bb    = (const float*)d_in[18];
    const float* wo    = (const float*)d_in[19];
    const float* bo    = (const float*)d_in[20];
    float* ws  = (float*)d_ws;
    float* out = (float*)d_out;

    bias_gemm<<<4096, 256, 0, stream>>>(z, wb, bb, ws + WW);
    proj_gemm<<<dim3(8, 24), 256, 0, stream>>>(
        s, wq, bq, wk, bk, wv, bv, wqp, bqp, wkp, bkp, wvp, bvp, rot, trans,
        ws + WPROJ, ws + WKT);
    score_kernel<<<NN, 1024, 0, stream>>>(ws + WPROJ, ws + WKT, ws + WW, mask, rot, trans, ws + WFEAT);
    pair_kernel<<<NN, 1024, 0, stream>>>(ws + WW, z, ws + WFEAT);
    out_gemm<<<dim3(8, 6, KC), 256, 0, stream>>>(ws + WFEAT, wo, ws + WOUTP);
    out_reduce<<<192, 256, 0, stream>>>(ws + WOUTP, bo, out);
}

// Round 8
// 344.256 us; speedup vs baseline: 1.3067x; 1.1703x over previous
//
#include <hip/hip_runtime.h>

#define NN 512
#define CS 384
#define CZ 128
#define NH 12
#define PROJW 1152
#define FEAT 2112
#define OUTC 384
#define KC 12            // split-K chunks for out_gemm
#define KTILES 11        // K-tiles of 16 per chunk (12*11*16 = 2112)

// workspace float offsets
#define WPROJ 0          // [512][1152]: q 0:192 | k 192:384 | v 384:576 | qp 576:720 | kp 720:864 | vp 864:1152
#define WFEAT 589824     // [512][2112]
#define WW    1671168    // [512*512][12]: bias -> normalized w ; REUSED later as split-K pout
#define WOUTP 1671168    // [12][512][384] split-K partials (written after pair_kernel done reading WW)
#define WKT   4816896    // [336][512]: kT rows 0:192 = k cols, 192:336 = rotated kp cols

// ---------------- K1a: bias = z @ wb + bb  -> ww[nm][12]  (4096 blocks, HBM-bound) ----------------
__global__ __launch_bounds__(256) void bias_gemm(
    const float* __restrict__ z,
    const float* __restrict__ wb, const float* __restrict__ bb,
    float* __restrict__ ww)
{
    __shared__ float zl[64*128];     // XOR-swizzled float4 rows
    __shared__ float sb[64*12];
    int tid = threadIdx.x;
    size_t r0 = (size_t)blockIdx.x * 64;          // global nm row base

    const float4* src = (const float4*)(z + r0*CZ);
    float4 v[8];
    #pragma unroll
    for (int k = 0; k < 8; ++k) v[k] = src[tid + k*256];
    #pragma unroll
    for (int k = 0; k < 8; ++k) {
        int i = tid + k*256;
        int r = i >> 5, c4 = i & 31;
        *(float4*)&zl[r*128 + ((c4 ^ (r & 7)) << 2)] = v[k];
    }
    __syncthreads();

    int r = tid & 63, hg = tid >> 6;              // wave-uniform hg
    int h0 = __builtin_amdgcn_readfirstlane(hg * 3);
    const float* wbp = wb + h0;
    float a0 = bb[h0], a1 = bb[h0+1], a2 = bb[h0+2];
    #pragma unroll 8
    for (int c4 = 0; c4 < 32; ++c4) {
        float4 zv = *(const float4*)&zl[r*128 + ((c4 ^ (r & 7)) << 2)];
        int cb = c4*4;
        a0 += zv.x*wbp[cb*12]     + zv.y*wbp[(cb+1)*12]     + zv.z*wbp[(cb+2)*12]     + zv.w*wbp[(cb+3)*12];
        a1 += zv.x*wbp[cb*12 + 1] + zv.y*wbp[(cb+1)*12 + 1] + zv.z*wbp[(cb+2)*12 + 1] + zv.w*wbp[(cb+3)*12 + 1];
        a2 += zv.x*wbp[cb*12 + 2] + zv.y*wbp[(cb+1)*12 + 2] + zv.z*wbp[(cb+2)*12 + 2] + zv.w*wbp[(cb+3)*12 + 2];
    }
    float* sd = &sb[r*12 + h0];
    sd[0] = a0; sd[1] = a1; sd[2] = a2;
    __syncthreads();
    if (tid < 192) ((float4*)(ww + r0*12))[tid] = ((const float4*)sb)[tid];
}

// ---------------- K1b: proj GEMM v2 (512x1152, K=384), 32x48 tiles, reg-prefetch ----------------
__global__ __launch_bounds__(256) void proj_gemm(
    const float* __restrict__ s,
    const float* __restrict__ wq, const float* __restrict__ bq,
    const float* __restrict__ wk, const float* __restrict__ bk,
    const float* __restrict__ wv, const float* __restrict__ bv,
    const float* __restrict__ wqp, const float* __restrict__ bqp,
    const float* __restrict__ wkp, const float* __restrict__ bkp,
    const float* __restrict__ wvp, const float* __restrict__ bvp,
    const float* __restrict__ rot, const float* __restrict__ trans,
    float* __restrict__ proj, float* __restrict__ kT)
{
    __shared__ float As[32*33];      // [k][m], stride 33
    __shared__ float Ws[32*52];      // [k][n], stride 52
    int tid = threadIdx.x;
    int gm0 = blockIdx.x * 32;       // 16 m-blocks
    int gc0 = blockIdx.y * 48;       // 24 c-blocks
    const float *w, *b; int ldw, lc0;
    if      (gc0 < 192) { w = wq;  b = bq;  ldw = 192; lc0 = gc0;       }
    else if (gc0 < 384) { w = wk;  b = bk;  ldw = 192; lc0 = gc0 - 192; }
    else if (gc0 < 576) { w = wv;  b = bv;  ldw = 192; lc0 = gc0 - 384; }
    else if (gc0 < 720) { w = wqp; b = bqp; ldw = 144; lc0 = gc0 - 576; }
    else if (gc0 < 864) { w = wkp; b = bkp; ldw = 144; lc0 = gc0 - 720; }
    else                { w = wvp; b = bvp; ldw = 288; lc0 = gc0 - 864; }

    int mi = tid >> 4, ni = tid & 15;
    int m0 = mi * 2, n0 = ni * 3;    // 2 m-rows x 3 n-cols per thread
    float acc[2][3] = {};

    float pa[4], pw[6], na[4], nw[6];
    // preload stage 0
    #pragma unroll
    for (int i = 0; i < 4; ++i) {
        int idx = tid + i*256;
        pa[i] = s[(gm0 + (idx >> 5))*CS + (idx & 31)];
    }
    #pragma unroll
    for (int i = 0; i < 6; ++i) {
        int idx = tid + i*256;
        int c = idx / 48, j = idx - c*48;
        pw[i] = w[c*ldw + lc0 + j];
    }

    for (int kt = 0; kt < 12; ++kt) {
        // store current stage to LDS
        #pragma unroll
        for (int i = 0; i < 4; ++i) {
            int idx = tid + i*256;
            As[(idx & 31)*33 + (idx >> 5)] = pa[i];
        }
        #pragma unroll
        for (int i = 0; i < 6; ++i) {
            int idx = tid + i*256;
            int c = idx / 48, j = idx - c*48;
            Ws[c*52 + j] = pw[i];
        }
        // prefetch next stage into regs (hides L2/HBM latency under inner loop)
        if (kt < 11) {
            int k0 = (kt + 1)*32;
            #pragma unroll
            for (int i = 0; i < 4; ++i) {
                int idx = tid + i*256;
                na[i] = s[(gm0 + (idx >> 5))*CS + k0 + (idx & 31)];
            }
            #pragma unroll
            for (int i = 0; i < 6; ++i) {
                int idx = tid + i*256;
                int c = idx / 48, j = idx - c*48;
                nw[i] = w[(k0 + c)*ldw + lc0 + j];
            }
        } else {
            #pragma unroll
            for (int i = 0; i < 4; ++i) na[i] = 0.f;
            #pragma unroll
            for (int i = 0; i < 6; ++i) nw[i] = 0.f;
        }
        __syncthreads();
        #pragma unroll
        for (int kk = 0; kk < 32; ++kk) {
            float a0 = As[kk*33 + m0], a1 = As[kk*33 + m0 + 1];
            float w0 = Ws[kk*52 + n0], w1 = Ws[kk*52 + n0 + 1], w2 = Ws[kk*52 + n0 + 2];
            acc[0][0] += a0*w0; acc[0][1] += a0*w1; acc[0][2] += a0*w2;
            acc[1][0] += a1*w0; acc[1][1] += a1*w1; acc[1][2] += a1*w2;
        }
        __syncthreads();
        #pragma unroll
        for (int i = 0; i < 4; ++i) pa[i] = na[i];
        #pragma unroll
        for (int i = 0; i < 6; ++i) pw[i] = nw[i];
    }

    float b0 = b[lc0 + n0], b1 = b[lc0 + n0 + 1], b2 = b[lc0 + n0 + 2];
    if (gc0 >= 576) {
        #pragma unroll
        for (int i = 0; i < 2; ++i) {
            int gm = gm0 + m0 + i;
            const float* R = rot + gm*9;
            const float* T = trans + gm*3;
            float x = acc[i][0] + b0, y = acc[i][1] + b1, zz = acc[i][2] + b2;
            float gx = R[0]*x + R[1]*y + R[2]*zz + T[0];
            float gy = R[3]*x + R[4]*y + R[5]*zz + T[1];
            float gz = R[6]*x + R[7]*y + R[8]*zz + T[2];
            float* dst = proj + (size_t)gm*PROJW + gc0 + n0;
            dst[0] = gx; dst[1] = gy; dst[2] = gz;
            if (gc0 >= 720 && gc0 < 864) {        // rotated kp -> kT rows 192..335
                int c = 192 + (gc0 - 720) + n0;
                kT[(size_t)(c+0)*NN + gm] = gx;
                kT[(size_t)(c+1)*NN + gm] = gy;
                kT[(size_t)(c+2)*NN + gm] = gz;
            }
        }
    } else {
        #pragma unroll
        for (int i = 0; i < 2; ++i) {
            int gm = gm0 + m0 + i;
            float v0 = acc[i][0] + b0, v1 = acc[i][1] + b1, v2 = acc[i][2] + b2;
            float* dst = proj + (size_t)gm*PROJW + gc0 + n0;
            dst[0] = v0; dst[1] = v1; dst[2] = v2;
            if (gc0 >= 192 && gc0 < 384) {        // k -> kT rows 0..191
                int c = gc0 - 192 + n0;
                kT[(size_t)(c+0)*NN + gm] = v0;
                kT[(size_t)(c+1)*NN + gm] = v1;
                kT[(size_t)(c+2)*NN + gm] = v2;
            }
        }
    }
}

// ---------------- K2: scores (kT) + softmax + write w + v_out scalar/points/norms ----------------
__global__ __launch_bounds__(512, 4) void score_kernel(
    const float* __restrict__ proj, const float* __restrict__ kT,
    float* __restrict__ ww,                      // bias in, normalized w out
    const int* __restrict__ mask,
    const float* __restrict__ rot, const float* __restrict__ trans,
    float* __restrict__ feat)
{
    int n = blockIdx.x, tid = threadIdx.x;
    __shared__ float s_e[NN*12];     // bias -> scores -> exp -> w, [m][12]
    __shared__ float s_q[336];       // q (192) + rotated qp (144)
    __shared__ float s_pts[288];
    __shared__ float s_red[384];
    __shared__ float s_M[NH], s_S[NH];

    // load bias rows + q row
    {
        const float4* src = (const float4*)(ww + (size_t)n*NN*12);
        float4* dst = (float4*)s_e;
        #pragma unroll
        for (int k = 0; k < 3; ++k) dst[tid + k*512] = src[tid + k*512];
    }
    if (tid < 336) s_q[tid] = proj[(size_t)n*PROJW + (tid < 192 ? tid : 384 + tid)];
    int mn = mask[n];
    __syncthreads();

    // scores via transposed k/kp (lane-coalesced kT loads)
    {
        int m = tid;
        bool ok = (mn != 0) && (mask[m] != 0);
        float sc[12];
        #pragma unroll 2
        for (int h = 0; h < NH; ++h) {
            const float* qh  = &s_q[h*16];
            const float* kTh = kT + (size_t)(h*16)*NN + m;
            float dot = 0.f;
            #pragma unroll
            for (int cc = 0; cc < 16; ++cc) dot += qh[cc] * kTh[(size_t)cc*NN];
            const float* qph  = &s_q[192 + h*12];
            const float* kpTh = kT + (size_t)(192 + h*12)*NN + m;
            float pts = 0.f;
            #pragma unroll
            for (int j = 0; j < 12; ++j) { float d = qph[j] - kpTh[(size_t)j*NN]; pts += d*d; }
            sc[h] = dot*0.25f - 0.5f*pts;
        }
        float* row = &s_e[m*12];
        #pragma unroll
        for (int h = 0; h < NH; ++h) {
            float v = sc[h] + row[h];
            row[h] = ok ? v : -1e30f;
        }
    }
    __syncthreads();
    // max
    if (tid < 384) {
        int i = tid / 12, h = tid - i*12;
        float mx = -1e30f;
        for (int mm = i*16; mm < i*16 + 16; ++mm) mx = fmaxf(mx, s_e[mm*12 + h]);
        s_red[tid] = mx;
    }
    __syncthreads();
    if (tid < NH) {
        float mx = -1e30f;
        #pragma unroll
        for (int i = 0; i < 32; ++i) mx = fmaxf(mx, s_red[i*12 + tid]);
        s_M[tid] = mx;
    }
    __syncthreads();
    // exp in place
    {
        float M[12];
        #pragma unroll
        for (int h = 0; h < NH; ++h) M[h] = s_M[h];
        float* row = &s_e[tid*12];
        float4 a = *(float4*)row, b4 = *(float4*)(row+4), c4 = *(float4*)(row+8);
        a.x = __expf(a.x - M[0]);  a.y = __expf(a.y - M[1]);
        a.z = __expf(a.z - M[2]);  a.w = __expf(a.w - M[3]);
        b4.x = __expf(b4.x - M[4]); b4.y = __expf(b4.y - M[5]);
        b4.z = __expf(b4.z - M[6]); b4.w = __expf(b4.w - M[7]);
        c4.x = __expf(c4.x - M[8]); c4.y = __expf(c4.y - M[9]);
        c4.z = __expf(c4.z - M[10]); c4.w = __expf(c4.w - M[11]);
        *(float4*)row = a; *(float4*)(row+4) = b4; *(float4*)(row+8) = c4;
    }
    __syncthreads();
    // sum
    if (tid < 384) {
        int i = tid / 12, h = tid - i*12;
        float sm = 0.f;
        for (int mm = i*16; mm < i*16 + 16; ++mm) sm += s_e[mm*12 + h];
        s_red[tid] = sm;
    }
    __syncthreads();
    if (tid < NH) {
        float sm = 0.f;
        #pragma unroll
        for (int i = 0; i < 32; ++i) sm += s_red[i*12 + tid];
        s_S[tid] = sm;
    }
    __syncthreads();
    // normalize in place
    {
        float iS[12];
        #pragma unroll
        for (int h = 0; h < NH; ++h) iS[h] = 1.0f / s_S[h];
        float* row = &s_e[tid*12];
        float4 a = *(float4*)row, b4 = *(float4*)(row+4), c4 = *(float4*)(row+8);
        a.x *= iS[0]; a.y *= iS[1]; a.z *= iS[2]; a.w *= iS[3];
        b4.x *= iS[4]; b4.y *= iS[5]; b4.z *= iS[6]; b4.w *= iS[7];
        c4.x *= iS[8]; c4.y *= iS[9]; c4.z *= iS[10]; c4.w *= iS[11];
        *(float4*)row = a; *(float4*)(row+4) = b4; *(float4*)(row+8) = c4;
    }
    __syncthreads();
    // write normalized w back for pair_kernel
    {
        float4* dst = (float4*)(ww + (size_t)n*NN*12);
        const float4* src = (const float4*)s_e;
        #pragma unroll
        for (int k = 0; k < 3; ++k) dst[tid + k*512] = src[tid + k*512];
    }

    float* fout = feat + (size_t)n * FEAT;

    // v_out scalar (192) + points (288)
    {
        int o = tid;
        if (o < 480) {
            int col, h; bool isPt = (o >= 192);
            if (!isPt) { col = 384 + o;       h = o >> 4; }
            else       { int p = o - 192; col = 864 + p; h = p / 24; }
            const float* pc = proj + col;
            float acc0 = 0.f, acc1 = 0.f;
            #pragma unroll 8
            for (int mm = 0; mm < NN; mm += 2) {
                acc0 += s_e[(mm  )*12 + h] * pc[(size_t)(mm  )*PROJW];
                acc1 += s_e[(mm+1)*12 + h] * pc[(size_t)(mm+1)*PROJW];
            }
            float acc = acc0 + acc1;
            if (!isPt) fout[h*176 + (o & 15)] = acc;
            else       s_pts[o - 192] = acc;
        }
    }
    __syncthreads();
    // local transform + norms
    if (tid < 96) {
        int h = tid >> 3, p = tid & 7;
        const float* R = rot + n*9;
        const float* T = trans + n*3;
        float x  = s_pts[h*24 + p*3]     - T[0];
        float y  = s_pts[h*24 + p*3 + 1] - T[1];
        float zz = s_pts[h*24 + p*3 + 2] - T[2];
        float lx = R[0]*x + R[3]*y + R[6]*zz;
        float ly = R[1]*x + R[4]*y + R[7]*zz;
        float lz = R[2]*x + R[5]*y + R[8]*zz;
        float* fo = fout + h*176 + 16;
        fo[p*3] = lx; fo[p*3+1] = ly; fo[p*3+2] = lz;
        fout[h*176 + 40 + p] = sqrtf(lx*lx + ly*ly + lz*lz);
    }
}

// ---------------- K3: pair features = w . z  (per n, z re-read from L3) ----------------
__global__ __launch_bounds__(512, 4) void pair_kernel(
    const float* __restrict__ ww, const float* __restrict__ z,
    float* __restrict__ feat)
{
    int n = blockIdx.x, tid = threadIdx.x;
    __shared__ float s_w[NN*12];
    __shared__ float s_p[4*NH*128];
    {
        const float4* src = (const float4*)(ww + (size_t)n*NN*12);
        float4* dst = (float4*)s_w;
        #pragma unroll
        for (int k = 0; k < 3; ++k) dst[tid + k*512] = src[tid + k*512];
    }
    __syncthreads();
    int c = tid & 127, mh = tid >> 7;             // c column, m quarter
    const float* zb = z + ((size_t)n*NN + mh*128) * CZ + c;
    float pacc[12] = {};
    #pragma unroll 4
    for (int mm = 0; mm < 128; ++mm) {
        float zv = zb[(size_t)mm * CZ];
        const float* wr = &s_w[(mh*128 + mm)*12];           // broadcast across lanes
        float4 a = *(const float4*)wr, b4 = *(const float4*)(wr+4), c4 = *(const float4*)(wr+8);
        pacc[0] += a.x*zv;  pacc[1] += a.y*zv;  pacc[2] += a.z*zv;  pacc[3] += a.w*zv;
        pacc[4] += b4.x*zv; pacc[5] += b4.y*zv; pacc[6] += b4.z*zv; pacc[7] += b4.w*zv;
        pacc[8] += c4.x*zv; pacc[9] += c4.y*zv; pacc[10] += c4.z*zv; pacc[11] += c4.w*zv;
    }
    #pragma unroll
    for (int h = 0; h < NH; ++h) s_p[(mh*NH + h)*128 + c] = pacc[h];
    __syncthreads();
    {
        float* fout = feat + (size_t)n * FEAT;
        int cc = tid & 127, jh = tid >> 7;
        #pragma unroll
        for (int j = 0; j < 3; ++j) {
            int h = jh*3 + j;
            fout[h*176 + 48 + cc] = s_p[h*128 + cc] + s_p[(NH + h)*128 + cc]
                                  + s_p[(2*NH + h)*128 + cc] + s_p[(3*NH + h)*128 + cc];
        }
    }
}

// ---------------- K4: out GEMM split-K partials (512x384, K=2112, KC=12 x 176), reg-prefetch ----------------
__global__ __launch_bounds__(256) void out_gemm(
    const float* __restrict__ feat, const float* __restrict__ wo,
    float* __restrict__ pout)
{
    __shared__ float As[16*68];
    __shared__ float Ws[16*68];
    int tid = threadIdx.x;
    int gm0 = blockIdx.x * 64, gn0 = blockIdx.y * 64;
    int kc = blockIdx.z;
    int kbase = kc * (KTILES*16);
    int mi = tid >> 4, ni = tid & 15;
    int m0 = mi * 4, n0 = ni * 4;
    float acc[4][4] = {};

    int ar = tid >> 4, ac = tid & 15;
    int wr = tid >> 6, wc = tid & 63;

    float fa0, fa1, fa2, fa3, wa0, wa1, wa2, wa3;
    float fb0, fb1, fb2, fb3, wb0, wb1, wb2, wb3;
    {
        const float* fp = feat + (size_t)(gm0 + ar)*FEAT + kbase + ac;
        fa0 = fp[0]; fa1 = fp[16*FEAT]; fa2 = fp[32*FEAT]; fa3 = fp[48*FEAT];
        const float* wp = wo + (size_t)(kbase + wr)*OUTC + gn0 + wc;
        wa0 = wp[0]; wa1 = wp[4*OUTC]; wa2 = wp[8*OUTC]; wa3 = wp[12*OUTC];
    }
    for (int kt = 0; kt < KTILES; ++kt) {
        As[ac*68 + ar]      = fa0;
        As[ac*68 + ar + 16] = fa1;
        As[ac*68 + ar + 32] = fa2;
        As[ac*68 + ar + 48] = fa3;
        Ws[wr*68 + wc]        = wa0;
        Ws[(wr+4)*68 + wc]    = wa1;
        Ws[(wr+8)*68 + wc]    = wa2;
        Ws[(wr+12)*68 + wc]   = wa3;
        if (kt + 1 < KTILES) {
            int k0 = kbase + (kt+1)*16;
            const float* fp = feat + (size_t)(gm0 + ar)*FEAT + k0 + ac;
            fb0 = fp[0]; fb1 = fp[16*FEAT]; fb2 = fp[32*FEAT]; fb3 = fp[48*FEAT];
            const float* wp = wo + (size_t)(k0 + wr)*OUTC + gn0 + wc;
            wb0 = wp[0]; wb1 = wp[4*OUTC]; wb2 = wp[8*OUTC]; wb3 = wp[12*OUTC];
        }
        __syncthreads();
        #pragma unroll
        for (int kk = 0; kk < 16; ++kk) {
            float4 a = *(const float4*)&As[kk*68 + m0];
            float4 w = *(const float4*)&Ws[kk*68 + n0];
            acc[0][0] += a.x*w.x; acc[0][1] += a.x*w.y; acc[0][2] += a.x*w.z; acc[0][3] += a.x*w.w;
            acc[1][0] += a.y*w.x; acc[1][1] += a.y*w.y; acc[1][2] += a.y*w.z; acc[1][3] += a.y*w.w;
            acc[2][0] += a.z*w.x; acc[2][1] += a.z*w.y; acc[2][2] += a.z*w.z; acc[2][3] += a.z*w.w;
            acc[3][0] += a.w*w.x; acc[3][1] += a.w*w.y; acc[3][2] += a.w*w.z; acc[3][3] += a.w*w.w;
        }
        __syncthreads();
        fa0 = fb0; fa1 = fb1; fa2 = fb2; fa3 = fb3;
        wa0 = wb0; wa1 = wb1; wa2 = wb2; wa3 = wb3;
    }
    float* pb = pout + (size_t)kc * (NN*OUTC);
    #pragma unroll
    for (int i = 0; i < 4; ++i)
        *(float4*)&pb[(size_t)(gm0 + m0 + i)*OUTC + gn0 + n0] =
            make_float4(acc[i][0], acc[i][1], acc[i][2], acc[i][3]);
}

// ---------------- K5: reduce partials + bias ----------------
__global__ __launch_bounds__(256) void out_reduce(
    const float* __restrict__ pout, const float* __restrict__ bo,
    float* __restrict__ out)
{
    int idx4 = blockIdx.x * 256 + threadIdx.x;   // 49152 float4s
    int col4 = idx4 % 96;
    const float4* b4 = (const float4*)bo;
    float4 acc = b4[col4];
    #pragma unroll
    for (int kc = 0; kc < KC; ++kc) {
        float4 p = ((const float4*)(pout + (size_t)kc*(NN*OUTC)))[idx4];
        acc.x += p.x; acc.y += p.y; acc.z += p.z; acc.w += p.w;
    }
    ((float4*)out)[idx4] = acc;
}

extern "C" void kernel_launch(void* const* d_in, const int* in_sizes, int n_in,
                              void* d_out, int out_size, void* d_ws, size_t ws_size,
                              hipStream_t stream) {
    (void)in_sizes; (void)n_in; (void)out_size; (void)ws_size;
    const float* s     = (const float*)d_in[0];
    const float* z     = (const float*)d_in[1];
    const float* trans = (const float*)d_in[2];
    const float* rot   = (const float*)d_in[3];
    const int*   mask  = (const int*)d_in[4];
    const float* wq    = (const float*)d_in[5];
    const float* bq    = (const float*)d_in[6];
    const float* wk    = (const float*)d_in[7];
    const float* bk    = (const float*)d_in[8];
    const float* wv    = (const float*)d_in[9];
    const float* bv    = (const float*)d_in[10];
    const float* wqp   = (const float*)d_in[11];
    const float* bqp   = (const float*)d_in[12];
    const float* wkp   = (const float*)d_in[13];
    const float* bkp   = (const float*)d_in[14];
    const float* wvp   = (const float*)d_in[15];
    const float* bvp   = (const float*)d_in[16];
    const float* wb    = (const float*)d_in[17];
    const float* bb    = (const float*)d_in[18];
    const float* wo    = (const float*)d_in[19];
    const float* bo    = (const float*)d_in[20];
    float* ws  = (float*)d_ws;
    float* out = (float*)d_out;

    bias_gemm<<<4096, 256, 0, stream>>>(z, wb, bb, ws + WW);
    proj_gemm<<<dim3(16, 24), 256, 0, stream>>>(
        s, wq, bq, wk, bk, wv, bv, wqp, bqp, wkp, bkp, wvp, bvp, rot, trans,
        ws + WPROJ, ws + WKT);
    score_kernel<<<NN, 512, 0, stream>>>(ws + WPROJ, ws + WKT, ws + WW, mask, rot, trans, ws + WFEAT);
    pair_kernel<<<NN, 512, 0, stream>>>(ws + WW, z, ws + WFEAT);
    out_gemm<<<dim3(8, 6, KC), 256, 0, stream>>>(ws + WFEAT, wo, ws + WOUTP);
    out_reduce<<<192, 256, 0, stream>>>(ws + WOUTP, bo, out);
}